// Round 17
// baseline (496.470 us; speedup 1.0000x reference)
//
#include <hip/hip_runtime.h>
#include <hip/hip_bf16.h>

using bf16x8 = short __attribute__((ext_vector_type(8)));
using f32x16 = float __attribute__((ext_vector_type(16)));

#define MROWS 100352      // 2048*49
#define SCALE_Q 0.17677669529663687f

static __device__ __forceinline__ unsigned short f2bs(float f){
  unsigned u = __builtin_bit_cast(unsigned, f);
  unsigned r = (u + 0x7FFFu + ((u >> 16) & 1u)) >> 16;   // RNE
  return (unsigned short)r;
}
// HW packed fp32->bf16 (RNE): lo -> bits[15:0], hi -> bits[31:16]. One VALU op.
static __device__ __forceinline__ unsigned cvt_pk(float lo, float hi){
  unsigned r;
  asm("v_cvt_pk_bf16_f32 %0, %1, %2" : "=v"(r) : "v"(lo), "v"(hi));
  return r;
}

// ---------------- x -> bf16 cast (each thread: 8 elems) ----------------
__global__ void k_xcast(const float* __restrict__ x, short* __restrict__ xb){
  const int i = blockIdx.x*256 + threadIdx.x;
  const float4 u0 = *reinterpret_cast<const float4*>(x + (size_t)i*8);
  const float4 u1 = *reinterpret_cast<const float4*>(x + (size_t)i*8 + 4);
  union { bf16x8 v; unsigned u[4]; } t;
  t.u[0] = cvt_pk(u0.x, u0.y); t.u[1] = cvt_pk(u0.z, u0.w);
  t.u[2] = cvt_pk(u1.x, u1.y); t.u[3] = cvt_pk(u1.z, u1.w);
  *reinterpret_cast<bf16x8*>(xb + (size_t)i*8) = t.v;
}

// ---------------- weight conversion (transposed, head-permuted, q-scaled) + bias table ----------------
__global__ void k_convert(const float* __restrict__ qkvW, const float* __restrict__ qkvB,
                          const float* __restrict__ projW, const float* __restrict__ ab,
                          short* __restrict__ WqkvT, short* __restrict__ WpT,
                          float* __restrict__ bqkv, float* __restrict__ bias_exp){
  int i = blockIdx.x*256 + threadIdx.x;
  if (i < 1536*384){
    int c = i/384, f = i - c*384;
    int src; float sc = 1.0f;
    if (c < 512){ src = (c>>6)*192 + (c&63); if ((c&63) < 32) sc = SCALE_Q; }
    else        { int dv = c - 512; src = (dv>>7)*192 + 64 + (dv&127); }
    WqkvT[i] = (short)f2bs(qkvW[f*1536 + src] * sc);
    return;
  }
  i -= 1536*384;
  if (i < 384*1024){
    int j = i/1024, m = i - j*1024;
    WpT[i] = (short)f2bs(projW[m*384 + j]);
    return;
  }
  i -= 384*1024;
  if (i < 1536){
    int c = i; int src; float sc = 1.0f;
    if (c < 512){ src = (c>>6)*192 + (c&63); if ((c&63) < 32) sc = SCALE_Q; }
    else        { int dv = c - 512; src = (dv>>7)*192 + 64 + (dv&127); }
    bqkv[c] = qkvB[src] * sc;
    return;
  }
  i -= 1536;
  if (i < 8*64*49){
    int h = i / (64*49), rem = i - h*(64*49);
    int r = rem / 49, n = rem - r*49;
    float v = 0.0f;
    if (r < 49){
      int rh = r/7, rw = r - rh*7, ch = n/7, cw = n - ch*7;
      int dh = rh>ch?rh-ch:ch-rh, dw = rw>cw?rw-cw:cw-rw;
      v = ab[h*49 + dh*7 + dw];
    }
    bias_exp[i] = v;
  }
}

// ---------------- qkv GEMM v7 (r13-verified, 188 us): tile 256x256, BK=32, TRI-buffer ----------------
// Per kt: vmcnt(4) -> s_barrier -> {ks0 reads+MFMA(prio1), stage(kt+2), ks1 reads+MFMA(prio1)}.
__global__ __launch_bounds__(512) void k_qkv7(const short* __restrict__ xb,
                                              const short* __restrict__ WqkvT,
                                              const float* __restrict__ bqkv,
                                              short* __restrict__ qkvbuf){
  __shared__ short lds3[3][512*32];   // per buf: A = [0,8192) shorts, B = [8192,16384)
  const int t = threadIdx.x;
  const int lane = t & 63, w = t >> 6;
  const int hi = lane >> 5, l31 = lane & 31;
  const int wm = w >> 1, wn = w & 1;          // 4M x 2N waves, wave-tile 64x128

  const int nwg = 6*392;                      // 2352, %8==0
  const int lin = blockIdx.x + 6*blockIdx.y;
  const int swz = (lin & 7)*(nwg>>3) + (lin>>3);
  const int slab = swz % 6, panel = swz / 6;
  const size_t R0 = (size_t)panel*256, C0 = (size_t)slab*256;

  const int srowl  = lane >> 2;                              // row within 16-row group
  const int schunk = ((lane & 3) ^ ((lane >> 3) & 3)) * 8;   // pre-swizzled source chunk (shorts)
  const short* aG0 = xb    + (R0 + (size_t)(w*16       + srowl))*384 + schunk;
  const short* aG1 = xb    + (R0 + (size_t)((8+w)*16   + srowl))*384 + schunk;
  const short* bG0 = WqkvT + (C0 + (size_t)(w*16       + srowl))*384 + schunk;
  const short* bG1 = WqkvT + (C0 + (size_t)((8+w)*16   + srowl))*384 + schunk;

  auto stage = [&](int bufi, int kti){
    short* base = &lds3[bufi][0];
    __builtin_amdgcn_global_load_lds((const unsigned __attribute__((address_space(1)))*)(aG0 + kti*32),
        (unsigned __attribute__((address_space(3)))*)(base + w*512), 16, 0, 0);
    __builtin_amdgcn_global_load_lds((const unsigned __attribute__((address_space(1)))*)(aG1 + kti*32),
        (unsigned __attribute__((address_space(3)))*)(base + (8+w)*512), 16, 0, 0);
    __builtin_amdgcn_global_load_lds((const unsigned __attribute__((address_space(1)))*)(bG0 + kti*32),
        (unsigned __attribute__((address_space(3)))*)(base + 8192 + w*512), 16, 0, 0);
    __builtin_amdgcn_global_load_lds((const unsigned __attribute__((address_space(1)))*)(bG1 + kti*32),
        (unsigned __attribute__((address_space(3)))*)(base + 8192 + (8+w)*512), 16, 0, 0);
  };

  f32x16 acc[2][4];
  #pragma unroll
  for (int mt=0; mt<2; ++mt)
    #pragma unroll
    for (int nt=0; nt<4; ++nt) acc[mt][nt] = (f32x16)0.0f;

  stage(0, 0); stage(1, 1);

  int cur = 0;                     // kt % 3
  for (int kt=0; kt<12; ++kt){
    if (kt < 11) asm volatile("s_waitcnt vmcnt(4)" ::: "memory");
    else         asm volatile("s_waitcnt vmcnt(0)" ::: "memory");
    __builtin_amdgcn_s_barrier();

    const char* Ab = (const char*)&lds3[cur][0];
    const char* Bb = Ab + 16384;

    // ---- ks = 0 ----
    {
      bf16x8 aF[2], bF[4];
      #pragma unroll
      for (int mt=0; mt<2; ++mt){
        const int rA = wm*64 + mt*32 + l31;
        aF[mt] = *reinterpret_cast<const bf16x8*>(Ab + rA*64 + (((0|hi) ^ ((rA>>1)&3))<<4));
      }
      #pragma unroll
      for (int nt=0; nt<4; ++nt){
        const int rB = wn*128 + nt*32 + l31;
        bF[nt] = *reinterpret_cast<const bf16x8*>(Bb + rB*64 + (((0|hi) ^ ((rB>>1)&3))<<4));
      }
      __builtin_amdgcn_s_setprio(1);
      #pragma unroll
      for (int mt=0; mt<2; ++mt)
        #pragma unroll
        for (int nt=0; nt<4; ++nt)
          acc[mt][nt] = __builtin_amdgcn_mfma_f32_32x32x16_bf16(aF[mt], bF[nt], acc[mt][nt], 0,0,0);
      __builtin_amdgcn_s_setprio(0);
    }
    if (kt < 10){
      const int nb = (cur + 2 >= 3) ? cur - 1 : cur + 2;
      stage(nb, kt + 2);
    }
    // ---- ks = 1 ----
    {
      bf16x8 aF[2], bF[4];
      #pragma unroll
      for (int mt=0; mt<2; ++mt){
        const int rA = wm*64 + mt*32 + l31;
        aF[mt] = *reinterpret_cast<const bf16x8*>(Ab + rA*64 + (((2|hi) ^ ((rA>>1)&3))<<4));
      }
      #pragma unroll
      for (int nt=0; nt<4; ++nt){
        const int rB = wn*128 + nt*32 + l31;
        bF[nt] = *reinterpret_cast<const bf16x8*>(Bb + rB*64 + (((2|hi) ^ ((rB>>1)&3))<<4));
      }
      __builtin_amdgcn_s_setprio(1);
      #pragma unroll
      for (int mt=0; mt<2; ++mt)
        #pragma unroll
        for (int nt=0; nt<4; ++nt)
          acc[mt][nt] = __builtin_amdgcn_mfma_f32_32x32x16_bf16(aF[mt], bF[nt], acc[mt][nt], 0,0,0);
      __builtin_amdgcn_s_setprio(0);
    }
    cur = (cur == 2) ? 0 : cur + 1;
  }

  #pragma unroll
  for (int nt=0; nt<4; ++nt){
    const int c = (int)C0 + wn*128 + nt*32 + l31;
    const float bb = bqkv[c];
    #pragma unroll
    for (int mt=0; mt<2; ++mt){
      const size_t rbase = R0 + wm*64 + mt*32;
      #pragma unroll
      for (int rg=0; rg<16; rg+=2){
        const size_t r = rbase + (rg&3) + 8*(rg>>2) + 4*hi;   // rg even -> rows r, r+1
        const unsigned p = cvt_pk(acc[mt][nt][rg] + bb, acc[mt][nt][rg+1] + bb);
        qkvbuf[r*1536 + c]     = (short)(p & 0xFFFFu);
        qkvbuf[(r+1)*1536 + c] = (short)(p >> 16);
      }
    }
  }
}

// ---------------- proj GEMM: tile 128x128, BK=64, 4 waves (2x2), 3 slabs, chunked swizzle ----------------
__global__ __launch_bounds__(256) void k_proj4(const short* __restrict__ A,
                                               const short* __restrict__ Bw,
                                               const float* __restrict__ bias,
                                               float* __restrict__ out){
  __shared__ short Alds[128*64];
  __shared__ short Blds[128*64];
  const int lane = threadIdx.x & 63, w = threadIdx.x >> 6;
  const int hi = lane >> 5, l31 = lane & 31;
  const int wm = w >> 1, wn = w & 1;

  const int nwg = 3 * 784;                       // 2352, %8==0
  const int lin = blockIdx.x + 3 * blockIdx.y;
  const int swz = (lin & 7) * (nwg >> 3) + (lin >> 3);
  const int slab = swz % 3, panel = swz / 3;
  const size_t R0 = (size_t)panel * 128, C0 = (size_t)slab * 128;

  f32x16 acc[2][2];
  acc[0][0]=(f32x16)0.f; acc[0][1]=(f32x16)0.f; acc[1][0]=(f32x16)0.f; acc[1][1]=(f32x16)0.f;

  const int srow = lane >> 3;
  const int sG   = ((lane & 7) ^ srow) * 8;
  const short* aG = A  + (R0 + (size_t)(w*8 + srow))*1024 + sG;
  const short* bG = Bw + (C0 + (size_t)(w*8 + srow))*1024 + sG;

  for (int kt=0; kt<16; ++kt){
    #pragma unroll
    for (int j=0; j<4; ++j){
      __builtin_amdgcn_global_load_lds(
        (const unsigned int __attribute__((address_space(1)))*)(aG + (size_t)j*32*1024 + kt*64),
        (unsigned int __attribute__((address_space(3)))*)(&Alds[(j*32 + w*8)*64]), 16, 0, 0);
      __builtin_amdgcn_global_load_lds(
        (const unsigned int __attribute__((address_space(1)))*)(bG + (size_t)j*32*1024 + kt*64),
        (unsigned int __attribute__((address_space(3)))*)(&Blds[(j*32 + w*8)*64]), 16, 0, 0);
    }
    __syncthreads();
    #pragma unroll
    for (int ks=0; ks<4; ++ks){
      bf16x8 aF[2], bF[2];
      #pragma unroll
      for (int mt=0; mt<2; ++mt){
        const int rA = wm*64 + mt*32 + l31;
        aF[mt] = *reinterpret_cast<const bf16x8*>(
                   (const char*)Alds + rA*128 + ((((ks<<1)|hi) ^ (rA&7))<<4));
      }
      #pragma unroll
      for (int nt=0; nt<2; ++nt){
        const int rB = wn*64 + nt*32 + l31;
        bF[nt] = *reinterpret_cast<const bf16x8*>(
                   (const char*)Blds + rB*128 + ((((ks<<1)|hi) ^ (rB&7))<<4));
      }
      #pragma unroll
      for (int mt=0; mt<2; ++mt)
        #pragma unroll
        for (int nt=0; nt<2; ++nt)
          acc[mt][nt] = __builtin_amdgcn_mfma_f32_32x32x16_bf16(aF[mt], bF[nt], acc[mt][nt], 0,0,0);
    }
    __syncthreads();
  }

  #pragma unroll
  for (int nt=0; nt<2; ++nt){
    const int c = (int)C0 + wn*64 + nt*32 + l31;
    const float bb = bias[c];
    #pragma unroll
    for (int mt=0; mt<2; ++mt){
      const size_t rbase = R0 + wm*64 + mt*32;
      #pragma unroll
      for (int rg=0; rg<16; ++rg){
        const size_t r = rbase + (rg&3) + 8*(rg>>2) + 4*hi;
        out[r*384 + c] = acc[mt][nt][rg] + bb;
      }
    }
  }
}

// ---------------- attention: block = (batch, 4 heads), 256 thr; V staged in LDS (swizzled) ----------------
__global__ __launch_bounds__(256) void k_attn(const short* __restrict__ qkvbuf,
                                              const float* __restrict__ bias_exp, short* __restrict__ aout){
  const int lane = threadIdx.x & 63, w = threadIdx.x >> 6;
  const int hi = lane >> 5, l31 = lane & 31;
  const int b = blockIdx.x, hg = blockIdx.y;
  const int h = hg*4 + w;

  __shared__ short vlds[4*49*136];   // 53,312 B

  for (int i=0; i<13; ++i){
    const int n = i*4 + w;
    if (n < 49){
      const bf16x8 vv = *reinterpret_cast<const bf16x8*>(qkvbuf + (b*49+n)*1536 + 512 + hg*512 + lane*8);
      const int hh = lane >> 4;
      const int d0 = ((lane & 15) * 8) ^ (((n>>3)&1) << 5);
      *reinterpret_cast<bf16x8*>(&vlds[(hh*49 + n)*136 + d0]) = vv;
    }
  }
  __syncthreads();

  bf16x8 kf[2][2];
  #pragma unroll
  for (int mt=0; mt<2; ++mt){
    const int n = 32*mt + l31;
    #pragma unroll
    for (int ks=0; ks<2; ++ks)
      kf[mt][ks] = (n < 49)
        ? *reinterpret_cast<const bf16x8*>(qkvbuf + (b*49+n)*1536 + h*64 + 32 + ks*16 + hi*8)
        : (bf16x8)(short)0;
  }
  const short* vb = &vlds[w*49*136];
  const int dxbase = hi << 5;

  for (int rb=0; rb<2; ++rb){
    const int r = 32*rb + l31;
    bf16x8 qf[2];
    #pragma unroll
    for (int ks=0; ks<2; ++ks)
      qf[ks] = (r < 49)
        ? *reinterpret_cast<const bf16x8*>(qkvbuf + (b*49+r)*1536 + h*64 + ks*16 + hi*8)
        : (bf16x8)(short)0;

    f32x16 s[2];
    s[0] = (f32x16)0.0f; s[1] = (f32x16)0.0f;
    #pragma unroll
    for (int ks=0; ks<2; ++ks){
      s[0] = __builtin_amdgcn_mfma_f32_32x32x16_bf16(kf[0][ks], qf[ks], s[0], 0, 0, 0);
      s[1] = __builtin_amdgcn_mfma_f32_32x32x16_bf16(kf[1][ks], qf[ks], s[1], 0, 0, 0);
    }

    float mloc = -3.0e38f;
    #pragma unroll
    for (int mt=0; mt<2; ++mt)
      #pragma unroll
      for (int rg=0; rg<16; ++rg){
        const int n = 32*mt + (rg&3) + 8*(rg>>2) + 4*hi;
        float v = s[mt][rg];
        v = (n < 49) ? v + bias_exp[(h*64 + r)*49 + n] : -1.0e30f;
        s[mt][rg] = v;
        mloc = fmaxf(mloc, v);
      }
    const float mrow = fmaxf(mloc, __shfl_xor(mloc, 32));
    float sloc = 0.0f;
    #pragma unroll
    for (int mt=0; mt<2; ++mt)
      #pragma unroll
      for (int rg=0; rg<16; ++rg){
        const float p = __expf(s[mt][rg] - mrow);
        s[mt][rg] = p; sloc += p;
      }
    const float inv = 1.0f / (sloc + __shfl_xor(sloc, 32));
    #pragma unroll
    for (int mt=0; mt<2; ++mt)
      #pragma unroll
      for (int rg=0; rg<16; ++rg) s[mt][rg] *= inv;

    unsigned pk[8][2];
    #pragma unroll
    for (int o=0; o<8; ++o){
      const int mt = o>>2, base = 4*(o&3);
      pk[o][0] = cvt_pk(s[mt][base+0], s[mt][base+1]);
      pk[o][1] = cvt_pk(s[mt][base+2], s[mt][base+3]);
    }
    bf16x8 af[4];
    #pragma unroll
    for (int ks=0; ks<4; ++ks){
      const unsigned e0 = pk[2*ks][0],   e1 = pk[2*ks][1];
      const unsigned o0 = pk[2*ks+1][0], o1 = pk[2*ks+1][1];
      const unsigned own0 = hi ? o0 : e0, own1 = hi ? o1 : e1;
      const unsigned oth0 = hi ? e0 : o0, oth1 = hi ? e1 : o1;
      const unsigned sw0 = __shfl_xor(oth0, 32), sw1 = __shfl_xor(oth1, 32);
      const unsigned lo0 = hi ? sw0 : own0, lo1 = hi ? sw1 : own1;
      const unsigned h0  = hi ? own0 : sw0, h1  = hi ? own1 : sw1;
      union { bf16x8 v; unsigned u[4]; } t;
      t.u[0]=lo0; t.u[1]=lo1; t.u[2]=h0; t.u[3]=h1;
      af[ks] = t.v;
    }

    #pragma unroll
    for (int dt=0; dt<4; ++dt){
      const int dx = (dt*32 + l31) ^ dxbase;
      f32x16 acc = (f32x16)0.0f;
      #pragma unroll
      for (int ks=0; ks<4; ++ks){
        bf16x8 t;
        if (ks < 3){
          const int nb = ks*16 + hi*8;
          #pragma unroll
          for (int j=0; j<8; ++j) t[j] = vb[(nb + j)*136 + dx];
        } else {
          #pragma unroll
          for (int j=0; j<8; ++j) t[j] = 0;
          if (hi == 0) t[0] = vb[48*136 + (dt*32 + l31)];
        }
        acc = __builtin_amdgcn_mfma_f32_32x32x16_bf16(af[ks], t, acc, 0, 0, 0);
      }
      #pragma unroll
      for (int rg=0; rg<16; rg+=2){
        const int rr = 32*rb + (rg&3) + 8*(rg>>2) + 4*hi;   // rg even -> rows rr, rr+1
        const unsigned p = cvt_pk(acc[rg], acc[rg+1]);
        if (rr < 49)     aout[(b*49+rr)*1024 + h*128 + dt*32 + l31]     = (short)(p & 0xFFFFu);
        if (rr + 1 < 49) aout[(b*49+rr+1)*1024 + h*128 + dt*32 + l31]   = (short)(p >> 16);
      }
    }
  }
}

extern "C" void kernel_launch(void* const* d_in, const int* in_sizes, int n_in,
                              void* d_out, int out_size, void* d_ws, size_t ws_size,
                              hipStream_t stream) {
  const float* x     = (const float*)d_in[0];
  const float* qkvW  = (const float*)d_in[1];
  const float* qkvB  = (const float*)d_in[2];
  const float* projW = (const float*)d_in[3];
  const float* projB = (const float*)d_in[4];
  const float* ab    = (const float*)d_in[5];

  char* ws = (char*)d_ws;
  // xb (77 MB) aliased under aoutb (205.5 MB) — xb dead before k_attn writes aoutb
  short* aoutb = (short*)ws;
  short* xb    = (short*)ws;
  size_t off = (size_t)MROWS*1024*2;
  short* qkvbuf = (short*)(ws + off); off += (size_t)MROWS*1536*2;
  short* WqkvT  = (short*)(ws + off); off += (size_t)1536*384*2;
  short* WpT    = (short*)(ws + off); off += (size_t)384*1024*2;
  float* bqkv   = (float*)(ws + off); off += (size_t)1536*4;
  float* bias_exp = (float*)(ws + off); off += (size_t)8*64*49*4;
  if (ws_size < off) return;

  const int conv_total = 1536*384 + 384*1024 + 1536 + 8*64*49;
  k_convert<<<(conv_total + 255)/256, 256, 0, stream>>>(qkvW, qkvB, projW, ab,
                                                        WqkvT, WpT, bqkv, bias_exp);
  k_xcast<<<MROWS*384/8/256, 256, 0, stream>>>(x, xb);
  k_qkv7<<<dim3(6, 392), 512, 0, stream>>>(xb, WqkvT, bqkv, qkvbuf);
  k_attn<<<dim3(2048, 2), 256, 0, stream>>>(qkvbuf, bias_exp, aoutb);
  k_proj4<<<dim3(3, 784), 256, 0, stream>>>(aoutb, WpT, projB, (float*)d_out);
}

// Round 18
// 473.498 us; speedup vs baseline: 1.0485x; 1.0485x over previous
//
#include <hip/hip_runtime.h>
#include <hip/hip_bf16.h>

using bf16x8 = short __attribute__((ext_vector_type(8)));
using f32x16 = float __attribute__((ext_vector_type(16)));

#define MROWS 100352      // 2048*49
#define SCALE_Q 0.17677669529663687f

static __device__ __forceinline__ unsigned short f2bs(float f){
  unsigned u = __builtin_bit_cast(unsigned, f);
  unsigned r = (u + 0x7FFFu + ((u >> 16) & 1u)) >> 16;   // RNE
  return (unsigned short)r;
}
// HW packed fp32->bf16 (RNE): lo -> bits[15:0], hi -> bits[31:16]. One VALU op.
static __device__ __forceinline__ unsigned cvt_pk(float lo, float hi){
  unsigned r;
  asm("v_cvt_pk_bf16_f32 %0, %1, %2" : "=v"(r) : "v"(lo), "v"(hi));
  return r;
}

// ---------------- weight conversion (transposed, head-permuted, q-scaled) + bias table ----------------
__global__ void k_convert(const float* __restrict__ qkvW, const float* __restrict__ qkvB,
                          const float* __restrict__ projW, const float* __restrict__ ab,
                          short* __restrict__ WqkvT, short* __restrict__ WpT,
                          float* __restrict__ bqkv, float* __restrict__ bias_exp){
  int i = blockIdx.x*256 + threadIdx.x;
  if (i < 1536*384){
    int c = i/384, f = i - c*384;
    int src; float sc = 1.0f;
    if (c < 512){ src = (c>>6)*192 + (c&63); if ((c&63) < 32) sc = SCALE_Q; }
    else        { int dv = c - 512; src = (dv>>7)*192 + 64 + (dv&127); }
    WqkvT[i] = (short)f2bs(qkvW[f*1536 + src] * sc);
    return;
  }
  i -= 1536*384;
  if (i < 384*1024){
    int j = i/1024, m = i - j*1024;
    WpT[i] = (short)f2bs(projW[m*384 + j]);
    return;
  }
  i -= 384*1024;
  if (i < 1536){
    int c = i; int src; float sc = 1.0f;
    if (c < 512){ src = (c>>6)*192 + (c&63); if ((c&63) < 32) sc = SCALE_Q; }
    else        { int dv = c - 512; src = (dv>>7)*192 + 64 + (dv&127); }
    bqkv[c] = qkvB[src] * sc;
    return;
  }
  i -= 1536;
  if (i < 8*64*49){
    int h = i / (64*49), rem = i - h*(64*49);
    int r = rem / 49, n = rem - r*49;
    float v = 0.0f;
    if (r < 49){
      int rh = r/7, rw = r - rh*7, ch = n/7, cw = n - ch*7;
      int dh = rh>ch?rh-ch:ch-rh, dw = rw>cw?rw-cw:cw-rw;
      v = ab[h*49 + dh*7 + dw];
    }
    bias_exp[i] = v;
  }
}

// ---------------- qkv GEMM v3b: tile 128x256, BK=64, 8 waves; cvt_pk fused-cast A ----------------
__global__ __launch_bounds__(512) void k_qkv3(const float* __restrict__ x,
                                              const short* __restrict__ WqkvT,
                                              const float* __restrict__ bqkv,
                                              short* __restrict__ qkvbuf){
  __shared__ short Alds[128*64];
  __shared__ short Blds[256*64];
  const int lane = threadIdx.x & 63, w = threadIdx.x >> 6;
  const int hi = lane >> 5, l31 = lane & 31;
  const int wm = w >> 2, wn = w & 3;

  const int nwg = 6*784;
  const int lin = blockIdx.x + 6*blockIdx.y;
  const int swz = (lin & 7)*(nwg>>3) + (lin>>3);
  const int slab = swz % 6, panel = swz / 6;
  const size_t R0 = (size_t)panel*128, C0 = (size_t)slab*256;

  // A staging geometry (fused cast): thread -> row rs, fp32 16-col block cb
  const int rs = threadIdx.x >> 2;
  const int cb = threadIdx.x & 3;
  const float* xrow = x + (R0 + rs)*384 + cb*16;
  const int adr0 = rs*64 + (((2*cb)   ^ (rs&7))<<3);   // shorts; swizzled chunk addr
  const int adr1 = rs*64 + (((2*cb+1) ^ (rs&7))<<3);

  // B staging geometry (gload_lds, pre-swizzled source)
  const int srow = lane >> 3;
  const int sG   = ((lane & 7) ^ srow) * 8;
  const short* bG = WqkvT + (C0 + (size_t)(w*8 + srow))*384 + sG;

  auto cvt8 = [](const float4& a, const float4& b)->bf16x8 {
    union { bf16x8 v; unsigned u[4]; } t;
    t.u[0] = cvt_pk(a.x, a.y); t.u[1] = cvt_pk(a.z, a.w);
    t.u[2] = cvt_pk(b.x, b.y); t.u[3] = cvt_pk(b.z, b.w);
    return t.v;
  };

  // prologue: stage A(0) + B(0)
  {
    const float4 g0 = *reinterpret_cast<const float4*>(xrow);
    const float4 g1 = *reinterpret_cast<const float4*>(xrow+4);
    const float4 g2 = *reinterpret_cast<const float4*>(xrow+8);
    const float4 g3 = *reinterpret_cast<const float4*>(xrow+12);
    *reinterpret_cast<bf16x8*>(&Alds[adr0]) = cvt8(g0, g1);
    *reinterpret_cast<bf16x8*>(&Alds[adr1]) = cvt8(g2, g3);
    #pragma unroll
    for (int j=0; j<4; ++j)
      __builtin_amdgcn_global_load_lds(
        (const unsigned int __attribute__((address_space(1)))*)(bG + (size_t)j*64*384),
        (unsigned int __attribute__((address_space(3)))*)(&Blds[(j*64 + w*8)*64]), 16, 0, 0);
  }
  __syncthreads();

  f32x16 acc[2][2];
  acc[0][0]=(f32x16)0.f; acc[0][1]=(f32x16)0.f; acc[1][0]=(f32x16)0.f; acc[1][1]=(f32x16)0.f;

  for (int kt=0; kt<6; ++kt){
    float4 g0,g1,g2,g3;
    if (kt < 5){
      const float* p = xrow + (kt+1)*64;
      g0 = *reinterpret_cast<const float4*>(p);
      g1 = *reinterpret_cast<const float4*>(p+4);
      g2 = *reinterpret_cast<const float4*>(p+8);
      g3 = *reinterpret_cast<const float4*>(p+12);
    }
    #pragma unroll
    for (int ks=0; ks<4; ++ks){
      bf16x8 aF[2], bF[2];
      #pragma unroll
      for (int mt=0; mt<2; ++mt){
        const int rA = wm*64 + mt*32 + l31;
        aF[mt] = *reinterpret_cast<const bf16x8*>(
                   (const char*)Alds + rA*128 + ((((ks<<1)|hi) ^ (rA&7))<<4));
      }
      #pragma unroll
      for (int nt=0; nt<2; ++nt){
        const int rB = wn*64 + nt*32 + l31;
        bF[nt] = *reinterpret_cast<const bf16x8*>(
                   (const char*)Blds + rB*128 + ((((ks<<1)|hi) ^ (rB&7))<<4));
      }
      #pragma unroll
      for (int mt=0; mt<2; ++mt)
        #pragma unroll
        for (int nt=0; nt<2; ++nt)
          acc[mt][nt] = __builtin_amdgcn_mfma_f32_32x32x16_bf16(aF[mt], bF[nt], acc[mt][nt], 0,0,0);
    }
    __syncthreads();   // all waves done reading Alds/Blds(kt)
    if (kt < 5){
      *reinterpret_cast<bf16x8*>(&Alds[adr0]) = cvt8(g0, g1);
      *reinterpret_cast<bf16x8*>(&Alds[adr1]) = cvt8(g2, g3);
      #pragma unroll
      for (int j=0; j<4; ++j)
        __builtin_amdgcn_global_load_lds(
          (const unsigned int __attribute__((address_space(1)))*)(bG + (size_t)j*64*384 + (kt+1)*64),
          (unsigned int __attribute__((address_space(3)))*)(&Blds[(j*64 + w*8)*64]), 16, 0, 0);
    }
    __syncthreads();   // drains ds_write (lgkm) + gload_lds (vmcnt)
  }

  #pragma unroll
  for (int nt=0; nt<2; ++nt){
    const int c = (int)C0 + wn*64 + nt*32 + l31;
    const float bb = bqkv[c];
    #pragma unroll
    for (int mt=0; mt<2; ++mt){
      const size_t rbase = R0 + wm*64 + mt*32;
      #pragma unroll
      for (int rg=0; rg<16; rg+=2){
        const size_t r = rbase + (rg&3) + 8*(rg>>2) + 4*hi;   // rg even -> rows r, r+1
        const unsigned p = cvt_pk(acc[mt][nt][rg] + bb, acc[mt][nt][rg+1] + bb);
        qkvbuf[r*1536 + c]     = (short)(p & 0xFFFFu);
        qkvbuf[(r+1)*1536 + c] = (short)(p >> 16);
      }
    }
  }
}

// ---------------- proj GEMM: tile 128x128, BK=64, 4 waves (2x2), 3 slabs, chunked swizzle ----------------
__global__ __launch_bounds__(256) void k_proj4(const short* __restrict__ A,
                                               const short* __restrict__ Bw,
                                               const float* __restrict__ bias,
                                               float* __restrict__ out){
  __shared__ short Alds[128*64];
  __shared__ short Blds[128*64];
  const int lane = threadIdx.x & 63, w = threadIdx.x >> 6;
  const int hi = lane >> 5, l31 = lane & 31;
  const int wm = w >> 1, wn = w & 1;

  const int nwg = 3 * 784;                       // 2352, %8==0
  const int lin = blockIdx.x + 3 * blockIdx.y;
  const int swz = (lin & 7) * (nwg >> 3) + (lin >> 3);
  const int slab = swz % 3, panel = swz / 3;
  const size_t R0 = (size_t)panel * 128, C0 = (size_t)slab * 128;

  f32x16 acc[2][2];
  acc[0][0]=(f32x16)0.f; acc[0][1]=(f32x16)0.f; acc[1][0]=(f32x16)0.f; acc[1][1]=(f32x16)0.f;

  const int srow = lane >> 3;
  const int sG   = ((lane & 7) ^ srow) * 8;
  const short* aG = A  + (R0 + (size_t)(w*8 + srow))*1024 + sG;
  const short* bG = Bw + (C0 + (size_t)(w*8 + srow))*1024 + sG;

  for (int kt=0; kt<16; ++kt){
    #pragma unroll
    for (int j=0; j<4; ++j){
      __builtin_amdgcn_global_load_lds(
        (const unsigned int __attribute__((address_space(1)))*)(aG + (size_t)j*32*1024 + kt*64),
        (unsigned int __attribute__((address_space(3)))*)(&Alds[(j*32 + w*8)*64]), 16, 0, 0);
      __builtin_amdgcn_global_load_lds(
        (const unsigned int __attribute__((address_space(1)))*)(bG + (size_t)j*32*1024 + kt*64),
        (unsigned int __attribute__((address_space(3)))*)(&Blds[(j*32 + w*8)*64]), 16, 0, 0);
    }
    __syncthreads();
    #pragma unroll
    for (int ks=0; ks<4; ++ks){
      bf16x8 aF[2], bF[2];
      #pragma unroll
      for (int mt=0; mt<2; ++mt){
        const int rA = wm*64 + mt*32 + l31;
        aF[mt] = *reinterpret_cast<const bf16x8*>(
                   (const char*)Alds + rA*128 + ((((ks<<1)|hi) ^ (rA&7))<<4));
      }
      #pragma unroll
      for (int nt=0; nt<2; ++nt){
        const int rB = wn*64 + nt*32 + l31;
        bF[nt] = *reinterpret_cast<const bf16x8*>(
                   (const char*)Blds + rB*128 + ((((ks<<1)|hi) ^ (rB&7))<<4));
      }
      #pragma unroll
      for (int mt=0; mt<2; ++mt)
        #pragma unroll
        for (int nt=0; nt<2; ++nt)
          acc[mt][nt] = __builtin_amdgcn_mfma_f32_32x32x16_bf16(aF[mt], bF[nt], acc[mt][nt], 0,0,0);
    }
    __syncthreads();
  }

  #pragma unroll
  for (int nt=0; nt<2; ++nt){
    const int c = (int)C0 + wn*64 + nt*32 + l31;
    const float bb = bias[c];
    #pragma unroll
    for (int mt=0; mt<2; ++mt){
      const size_t rbase = R0 + wm*64 + mt*32;
      #pragma unroll
      for (int rg=0; rg<16; ++rg){
        const size_t r = rbase + (rg&3) + 8*(rg>>2) + 4*hi;
        out[r*384 + c] = acc[mt][nt][rg] + bb;
      }
    }
  }
}

// ---------------- attention: block = (batch, 4 heads), 256 thr; V staged in LDS (swizzled) ----------------
__global__ __launch_bounds__(256) void k_attn(const short* __restrict__ qkvbuf,
                                              const float* __restrict__ bias_exp, short* __restrict__ aout){
  const int lane = threadIdx.x & 63, w = threadIdx.x >> 6;
  const int hi = lane >> 5, l31 = lane & 31;
  const int b = blockIdx.x, hg = blockIdx.y;
  const int h = hg*4 + w;

  __shared__ short vlds[4*49*136];   // 53,312 B

  for (int i=0; i<13; ++i){
    const int n = i*4 + w;
    if (n < 49){
      const bf16x8 vv = *reinterpret_cast<const bf16x8*>(qkvbuf + (b*49+n)*1536 + 512 + hg*512 + lane*8);
      const int hh = lane >> 4;
      const int d0 = ((lane & 15) * 8) ^ (((n>>3)&1) << 5);
      *reinterpret_cast<bf16x8*>(&vlds[(hh*49 + n)*136 + d0]) = vv;
    }
  }
  __syncthreads();

  bf16x8 kf[2][2];
  #pragma unroll
  for (int mt=0; mt<2; ++mt){
    const int n = 32*mt + l31;
    #pragma unroll
    for (int ks=0; ks<2; ++ks)
      kf[mt][ks] = (n < 49)
        ? *reinterpret_cast<const bf16x8*>(qkvbuf + (b*49+n)*1536 + h*64 + 32 + ks*16 + hi*8)
        : (bf16x8)(short)0;
  }
  const short* vb = &vlds[w*49*136];
  const int dxbase = hi << 5;

  for (int rb=0; rb<2; ++rb){
    const int r = 32*rb + l31;
    bf16x8 qf[2];
    #pragma unroll
    for (int ks=0; ks<2; ++ks)
      qf[ks] = (r < 49)
        ? *reinterpret_cast<const bf16x8*>(qkvbuf + (b*49+r)*1536 + h*64 + ks*16 + hi*8)
        : (bf16x8)(short)0;

    f32x16 s[2];
    s[0] = (f32x16)0.0f; s[1] = (f32x16)0.0f;
    #pragma unroll
    for (int ks=0; ks<2; ++ks){
      s[0] = __builtin_amdgcn_mfma_f32_32x32x16_bf16(kf[0][ks], qf[ks], s[0], 0, 0, 0);
      s[1] = __builtin_amdgcn_mfma_f32_32x32x16_bf16(kf[1][ks], qf[ks], s[1], 0, 0, 0);
    }

    float mloc = -3.0e38f;
    #pragma unroll
    for (int mt=0; mt<2; ++mt)
      #pragma unroll
      for (int rg=0; rg<16; ++rg){
        const int n = 32*mt + (rg&3) + 8*(rg>>2) + 4*hi;
        float v = s[mt][rg];
        v = (n < 49) ? v + bias_exp[(h*64 + r)*49 + n] : -1.0e30f;
        s[mt][rg] = v;
        mloc = fmaxf(mloc, v);
      }
    const float mrow = fmaxf(mloc, __shfl_xor(mloc, 32));
    float sloc = 0.0f;
    #pragma unroll
    for (int mt=0; mt<2; ++mt)
      #pragma unroll
      for (int rg=0; rg<16; ++rg){
        const float p = __expf(s[mt][rg] - mrow);
        s[mt][rg] = p; sloc += p;
      }
    const float inv = 1.0f / (sloc + __shfl_xor(sloc, 32));
    #pragma unroll
    for (int mt=0; mt<2; ++mt)
      #pragma unroll
      for (int rg=0; rg<16; ++rg) s[mt][rg] *= inv;

    unsigned pk[8][2];
    #pragma unroll
    for (int o=0; o<8; ++o){
      const int mt = o>>2, base = 4*(o&3);
      pk[o][0] = cvt_pk(s[mt][base+0], s[mt][base+1]);
      pk[o][1] = cvt_pk(s[mt][base+2], s[mt][base+3]);
    }
    bf16x8 af[4];
    #pragma unroll
    for (int ks=0; ks<4; ++ks){
      const unsigned e0 = pk[2*ks][0],   e1 = pk[2*ks][1];
      const unsigned o0 = pk[2*ks+1][0], o1 = pk[2*ks+1][1];
      const unsigned own0 = hi ? o0 : e0, own1 = hi ? o1 : e1;
      const unsigned oth0 = hi ? e0 : o0, oth1 = hi ? e1 : o1;
      const unsigned sw0 = __shfl_xor(oth0, 32), sw1 = __shfl_xor(oth1, 32);
      const unsigned lo0 = hi ? sw0 : own0, lo1 = hi ? sw1 : own1;
      const unsigned h0  = hi ? own0 : sw0, h1  = hi ? own1 : sw1;
      union { bf16x8 v; unsigned u[4]; } t;
      t.u[0]=lo0; t.u[1]=lo1; t.u[2]=h0; t.u[3]=h1;
      af[ks] = t.v;
    }

    #pragma unroll
    for (int dt=0; dt<4; ++dt){
      const int dx = (dt*32 + l31) ^ dxbase;
      f32x16 acc = (f32x16)0.0f;
      #pragma unroll
      for (int ks=0; ks<4; ++ks){
        bf16x8 t;
        if (ks < 3){
          const int nb = ks*16 + hi*8;
          #pragma unroll
          for (int j=0; j<8; ++j) t[j] = vb[(nb + j)*136 + dx];
        } else {
          #pragma unroll
          for (int j=0; j<8; ++j) t[j] = 0;
          if (hi == 0) t[0] = vb[48*136 + (dt*32 + l31)];
        }
        acc = __builtin_amdgcn_mfma_f32_32x32x16_bf16(af[ks], t, acc, 0, 0, 0);
      }
      #pragma unroll
      for (int rg=0; rg<16; rg+=2){
        const int rr = 32*rb + (rg&3) + 8*(rg>>2) + 4*hi;   // rg even -> rows rr, rr+1
        const unsigned p = cvt_pk(acc[rg], acc[rg+1]);
        if (rr < 49)     aout[(b*49+rr)*1024 + h*128 + dt*32 + l31]     = (short)(p & 0xFFFFu);
        if (rr + 1 < 49) aout[(b*49+rr+1)*1024 + h*128 + dt*32 + l31]   = (short)(p >> 16);
      }
    }
  }
}

extern "C" void kernel_launch(void* const* d_in, const int* in_sizes, int n_in,
                              void* d_out, int out_size, void* d_ws, size_t ws_size,
                              hipStream_t stream) {
  const float* x     = (const float*)d_in[0];
  const float* qkvW  = (const float*)d_in[1];
  const float* qkvB  = (const float*)d_in[2];
  const float* projW = (const float*)d_in[3];
  const float* projB = (const float*)d_in[4];
  const float* ab    = (const float*)d_in[5];

  char* ws = (char*)d_ws;
  short* aoutb = (short*)ws;
  size_t off = (size_t)MROWS*1024*2;
  short* qkvbuf = (short*)(ws + off); off += (size_t)MROWS*1536*2;
  short* WqkvT  = (short*)(ws + off); off += (size_t)1536*384*2;
  short* WpT    = (short*)(ws + off); off += (size_t)384*1024*2;
  float* bqkv   = (float*)(ws + off); off += (size_t)1536*4;
  float* bias_exp = (float*)(ws + off); off += (size_t)8*64*49*4;
  if (ws_size < off) return;

  const int conv_total = 1536*384 + 384*1024 + 1536 + 8*64*49;
  k_convert<<<(conv_total + 255)/256, 256, 0, stream>>>(qkvW, qkvB, projW, ab,
                                                        WqkvT, WpT, bqkv, bias_exp);
  k_qkv3<<<dim3(6, 784), 512, 0, stream>>>(x, WqkvT, bqkv, qkvbuf);
  k_attn<<<dim3(2048, 2), 256, 0, stream>>>(qkvbuf, bias_exp, aoutb);
  k_proj4<<<dim3(3, 784), 256, 0, stream>>>(aoutb, WpT, projB, (float*)d_out);
}